// Round 1
// 460.279 us; speedup vs baseline: 1.0116x; 1.0116x over previous
//
#include <hip/hip_runtime.h>
#include <hip/hip_bf16.h>

// Problem constants
#define NN 40960      // nodes
#define NE 163840     // edges
#define NB 1024       // graphs

typedef __attribute__((ext_vector_type(8))) short short8;
typedef __attribute__((ext_vector_type(4))) float floatx4;

__device__ inline unsigned short f2bf(float f) {
    union { float f; unsigned u; } v; v.f = f;
    unsigned r = v.u + 0x7fffu + ((v.u >> 16) & 1u);
    return (unsigned short)(r >> 16);
}
__device__ inline float bf2f(unsigned short s) {
    union { unsigned u; float f; } v; v.u = ((unsigned)s) << 16; return v.f;
}
__device__ inline unsigned pack2bf(float lo, float hi) {
    return (unsigned)f2bf(lo) | ((unsigned)f2bf(hi) << 16);
}

// ---------------- workspace layout (float elements) ----------------
static const size_t o_dinv = 0, o_g312 = 40960, o_g1024 = 360448, o_xc = 1409024,
                    o_f1 = 1802240, o_f2 = 2850816, o_b1v = 3375104, o_b2v = 3375232,
                    o_iws = 3375360, o_bufA = 3621124, o_bufB = 16400644;
// bufA: T @0 | U16 @+851968 (bf16) | Vt16 @+2200000 (128x15008 bf16)
//       | Wt @+3200000 (transposed bf16 weights) | Wc2r @+4000000 | Wc1r @+4200000 | Btb @+4400000
// bufB: aggb @0 (NN*160 shorts max) | h16 @5.5M

// ---------------- CSR build ----------------
__global__ void k_hist(const int* __restrict__ dst, int* __restrict__ cnt) {
    int e = blockIdx.x * 256 + threadIdx.x;
    if (e < NE) atomicAdd(&cnt[dst[e]], 1);
}

__global__ __launch_bounds__(1024) void k_scan1(const int* __restrict__ cnt, int* __restrict__ offTmp,
                                                int* __restrict__ blockSum, float* __restrict__ dinv) {
    __shared__ int lds[1024];
    int tid = threadIdx.x;
    int i = blockIdx.x * 1024 + tid;
    int v = cnt[i];
    dinv[i] = rsqrtf((float)v + 1.0f);  // deg = in-count + self loop
    lds[tid] = v;
    __syncthreads();
    for (int s = 1; s < 1024; s <<= 1) {
        int t = (tid >= s) ? lds[tid - s] : 0;
        __syncthreads();
        lds[tid] += t;
        __syncthreads();
    }
    offTmp[i] = lds[tid] - v;  // local exclusive
    if (tid == 1023) blockSum[blockIdx.x] = lds[1023];
}

__global__ __launch_bounds__(64) void k_scan2(const int* __restrict__ blockSum, int* __restrict__ blockOff) {
    int l = threadIdx.x;
    int s = (l < 40) ? blockSum[l] : 0;
    int orig = s;
    for (int d = 1; d < 64; d <<= 1) {
        int t = __shfl_up(s, d);
        if (l >= d) s += t;
    }
    if (l < 40) blockOff[l] = s - orig;
}

__global__ __launch_bounds__(1024) void k_scan3(int* __restrict__ off, int* __restrict__ cur,
                                                const int* __restrict__ blockOff) {
    int i = blockIdx.x * 1024 + threadIdx.x;
    int o = off[i] + blockOff[blockIdx.x];
    off[i] = o;
    cur[i] = o;
    if (i == NN - 1) off[NN] = NE;
}

__global__ void k_fill(const int* __restrict__ ei, int* __restrict__ cur, int* __restrict__ srcOut) {
    int e = blockIdx.x * 256 + threadIdx.x;
    if (e >= NE) return;
    int s = ei[e], d = ei[NE + e];
    int pos = atomicAdd(&cur[d], 1);
    srcOut[pos] = s;
}

// ---------------- fused weight transpose-convert: all 7 weights -> padded bf16 [N64, Kpad] ----
__global__ __launch_bounds__(256) void k_cvt_wt(const float* __restrict__ W1, const float* __restrict__ W2,
                                                const float* __restrict__ W3, const float* __restrict__ Wg1,
                                                const float* __restrict__ Wg2, const float* __restrict__ Wf1,
                                                const float* __restrict__ Wf2, unsigned short* __restrict__ dst) {
    const int cum[8]  = {0, 128, 320, 640, 1664, 1792, 2816, 3328};
    const int KP[7]   = {96, 96, 160, 320, 1024, 384, 1024};
    const int KB[7]   = {78, 78, 156, 312, 1024, 384, 1024};
    const int NNm[7]  = {78, 156, 312, 1024, 128, 1024, 512};
    const size_t OFF[7] = {0, 12288, 30720, 81920, 409600, 540672, 933888};
    int m = 0;
    int bx = blockIdx.x;
    while (m < 6 && bx >= cum[m + 1]) m++;
    int r = bx - cum[m];
    const float* src = (m == 0) ? W1 : (m == 1) ? W2 : (m == 2) ? W3 : (m == 3) ? Wg1
                     : (m == 4) ? Wg2 : (m == 5) ? Wf1 : Wf2;
    int kp = KP[m], kb = KB[m], nn = NNm[m];
    unsigned short* d = dst + OFF[m] + (size_t)r * kp;
    for (int k = threadIdx.x; k < kp; k += 256) {
        float v = (r < nn && k < kb) ? src[(size_t)k * nn + r] : 0.f;
        d[k] = f2bf(v);
    }
}

// ---------------- GCN aggregation, layer 1: fp32 x in, bf16 out padded to 96. 2 cols/thread ----
__global__ __launch_bounds__(64) void k_agg_x(const float* __restrict__ x, const float* __restrict__ dinv,
                                              const int* __restrict__ off, const int* __restrict__ srcs,
                                              unsigned* __restrict__ out) {
    int n = blockIdx.x;
    int f = threadIdx.x;          // uint column (2 floats)
    if (f >= 48) return;
    if (f >= 39) { out[(size_t)n * 48 + f] = 0; return; }
    float di = dinv[n];
    float2 sv = *(const float2*)&x[(size_t)n * 78 + 2 * f];
    float a0 = sv.x * di * di, a1 = sv.y * di * di;
    int e0 = off[n], e1 = off[n + 1];
    int e = e0;
    for (; e + 4 <= e1; e += 4) {
        int s0 = srcs[e], s1 = srcs[e + 1], s2 = srcs[e + 2], s3 = srcs[e + 3];
        float d0 = dinv[s0] * di, d1 = dinv[s1] * di, d2 = dinv[s2] * di, d3 = dinv[s3] * di;
        float2 v0 = *(const float2*)&x[(size_t)s0 * 78 + 2 * f];
        float2 v1 = *(const float2*)&x[(size_t)s1 * 78 + 2 * f];
        float2 v2 = *(const float2*)&x[(size_t)s2 * 78 + 2 * f];
        float2 v3 = *(const float2*)&x[(size_t)s3 * 78 + 2 * f];
        a0 += v0.x * d0 + v1.x * d1 + v2.x * d2 + v3.x * d3;
        a1 += v0.y * d0 + v1.y * d1 + v2.y * d2 + v3.y * d3;
    }
    for (; e < e1; e++) {
        int s = srcs[e];
        float dd = dinv[s] * di;
        float2 v = *(const float2*)&x[(size_t)s * 78 + 2 * f];
        a0 += v.x * dd; a1 += v.y * dd;
    }
    out[(size_t)n * 48 + f] = pack2bf(a0, a1);
}

// ---------------- GCN aggregation bf16 in/out, 2 cols/thread (F2 = F/2 uints per row) ----------------
__global__ void k_agg16(const unsigned* __restrict__ h, const float* __restrict__ dinv,
                        const int* __restrict__ off, const int* __restrict__ srcs,
                        unsigned* __restrict__ out, int F2) {
    int n = blockIdx.x;
    int f = threadIdx.x;
    if (f >= F2) return;
    float di = dinv[n];
    unsigned s0v = h[(size_t)n * F2 + f];
    float a0 = bf2f((unsigned short)(s0v & 0xffff)) * di * di;
    float a1 = bf2f((unsigned short)(s0v >> 16)) * di * di;
    int e0 = off[n], e1 = off[n + 1];
    int e = e0;
    for (; e + 4 <= e1; e += 4) {
        int s0 = srcs[e], s1 = srcs[e + 1], s2 = srcs[e + 2], s3 = srcs[e + 3];
        float d0 = dinv[s0] * di, d1 = dinv[s1] * di, d2 = dinv[s2] * di, d3 = dinv[s3] * di;
        unsigned v0 = h[(size_t)s0 * F2 + f];
        unsigned v1 = h[(size_t)s1 * F2 + f];
        unsigned v2 = h[(size_t)s2 * F2 + f];
        unsigned v3 = h[(size_t)s3 * F2 + f];
        a0 += bf2f((unsigned short)(v0 & 0xffff)) * d0 + bf2f((unsigned short)(v1 & 0xffff)) * d1
            + bf2f((unsigned short)(v2 & 0xffff)) * d2 + bf2f((unsigned short)(v3 & 0xffff)) * d3;
        a1 += bf2f((unsigned short)(v0 >> 16)) * d0 + bf2f((unsigned short)(v1 >> 16)) * d1
            + bf2f((unsigned short)(v2 >> 16)) * d2 + bf2f((unsigned short)(v3 >> 16)) * d3;
    }
    for (; e < e1; e++) {
        int s = srcs[e];
        float dd = dinv[s] * di;
        unsigned v = h[(size_t)s * F2 + f];
        a0 += bf2f((unsigned short)(v & 0xffff)) * dd;
        a1 += bf2f((unsigned short)(v >> 16)) * dd;
    }
    out[(size_t)n * F2 + f] = pack2bf(a0, a1);
}

// segment max over 40 consecutive nodes per graph; bf16 in (already relu'd), bf16 out padded to 320
__global__ void k_segmax16(const unsigned short* __restrict__ h, unsigned short* __restrict__ g) {
    int gr = blockIdx.x, f = threadIdx.x;
    if (f >= 320) return;
    if (f >= 312) { g[(size_t)gr * 320 + f] = 0; return; }
    float m = 0.0f;
    const unsigned short* base = h + (size_t)gr * 40 * 312 + f;
    for (int i = 0; i < 40; i++) m = fmaxf(m, bf2f(base[(size_t)i * 312]));
    g[(size_t)gr * 320 + f] = f2bf(m);
}

// ---------------- bf16 MFMA GEMM with transposed-bf16 B: C = A @ Bt^T ----------------
// A: bf16 [M,lda] (ABF16, zero-padded K) or fp32 [M,lda] with Klim valid columns.
// Bt: bf16 [>=gridX*64 rows, ldb] zero-padded. M multiple of 64. Kpad multiple of 32.
#define LDST 72
template <bool ABF16, bool OUTBF16, bool ATOMIC, bool RELU_OUT>
__global__ __launch_bounds__(256) void gemm_bt(const void* __restrict__ Av, const unsigned short* __restrict__ Bt,
                                               const float* __restrict__ bias, void* __restrict__ Cv,
                                               int Nn, int Npad, int Kpad, int Klim,
                                               int lda, int ldb, int ldc, int ksplit) {
    __shared__ __align__(16) unsigned short As[64 * LDST];
    __shared__ __align__(16) unsigned short Bs[64 * LDST];
    const float* Af = (const float*)Av;
    const unsigned short* A16 = (const unsigned short*)Av;
    float* Cf = (float*)Cv;
    unsigned short* C16 = (unsigned short*)Cv;
    int bn0 = blockIdx.x * 64;
    int bm0 = blockIdx.y * 64;
    int k0 = blockIdx.z * ksplit;
    int kend = k0 + ksplit; if (kend > Kpad) kend = Kpad;
    int tid = threadIdx.x;
    int w = tid >> 6, l = tid & 63, q = l >> 4, r = l & 15;
    int wr = w >> 1, wc = w & 1;

    floatx4 acc[2][2];
#pragma unroll
    for (int i = 0; i < 2; i++)
#pragma unroll
        for (int c = 0; c < 2; c++) acc[i][c] = (floatx4)0.0f;

    int mA = tid >> 2, kcA = (tid & 3) * 8;
    int nB = tid >> 2, kcB = (tid & 3) * 8;
    int gmA = bm0 + mA;
    int gnB = bn0 + nB;

    for (int kt = k0; kt < kend; kt += 32) {
        // ---- stage A ----
        if (ABF16) {
            *(short8*)&As[mA * LDST + kcA] = *(const short8*)(A16 + (size_t)gmA * lda + kt + kcA);
        } else {
            const float* Ap = Af + (size_t)gmA * lda + kt + kcA;
            float av[8];
            if (kt + kcA + 8 <= Klim) {
#pragma unroll
                for (int j = 0; j < 4; j++) {
                    float2 p = *(const float2*)(Ap + j * 2);
                    av[j * 2] = p.x; av[j * 2 + 1] = p.y;
                }
            } else {
#pragma unroll
                for (int j = 0; j < 8; j++) av[j] = (kt + kcA + j < Klim) ? Ap[j] : 0.f;
            }
            short8 sv;
#pragma unroll
            for (int j = 0; j < 8; j++) sv[j] = (short)f2bf(av[j]);
            *(short8*)&As[mA * LDST + kcA] = sv;
        }
        // ---- stage B: single short8 from transposed bf16 ----
        *(short8*)&Bs[nB * LDST + kcB] = *(const short8*)(Bt + (size_t)gnB * ldb + kt + kcB);
        __syncthreads();
        short8 a0 = *(const short8*)&As[(wr * 32 + r) * LDST + q * 8];
        short8 a1 = *(const short8*)&As[(wr * 32 + 16 + r) * LDST + q * 8];
        short8 b0 = *(const short8*)&Bs[(wc * 32 + r) * LDST + q * 8];
        short8 b1 = *(const short8*)&Bs[(wc * 32 + 16 + r) * LDST + q * 8];
        acc[0][0] = __builtin_amdgcn_mfma_f32_16x16x32_bf16(a0, b0, acc[0][0], 0, 0, 0);
        acc[0][1] = __builtin_amdgcn_mfma_f32_16x16x32_bf16(a0, b1, acc[0][1], 0, 0, 0);
        acc[1][0] = __builtin_amdgcn_mfma_f32_16x16x32_bf16(a1, b0, acc[1][0], 0, 0, 0);
        acc[1][1] = __builtin_amdgcn_mfma_f32_16x16x32_bf16(a1, b1, acc[1][1], 0, 0, 0);
        __syncthreads();
    }

    // ---- epilogue: C/D layout col=lane&15, row=(lane>>4)*4+reg ----
#pragma unroll
    for (int c2 = 0; c2 < 2; c2++) {
        int col = bn0 + wc * 32 + c2 * 16 + r;
        if (col >= Npad) continue;
        bool live = col < Nn;
        float bv = (bias && live) ? bias[col] : 0.f;
#pragma unroll
        for (int i = 0; i < 2; i++) {
#pragma unroll
            for (int v = 0; v < 4; v++) {
                int row = bm0 + wr * 32 + i * 16 + q * 4 + v;
                float val = live ? (acc[i][c2][v] + bv) : 0.f;
                if (RELU_OUT) val = fmaxf(val, 0.f);
                if (OUTBF16) {
                    C16[(size_t)row * ldc + col] = live ? f2bf(val) : (unsigned short)0;
                } else if (live) {
                    if (ATOMIC) atomicAdd(&Cf[(size_t)row * ldc + col], val);
                    else Cf[(size_t)row * ldc + col] = val;
                }
            }
        }
    }
}

// ---------------- dedicated t1 GEMM: C[1024,128] += A[1024,15000]fp32 @ Vt16[128,15008]bf16^T ----
// Latency-optimized streaming split-K GEMM:
//  - tile 64(M) x 128(N), one block covers all N -> A staged once per (y,z)
//  - double-buffered LDS, depth-1 register prefetch
//  - RAW s_barrier + explicit lgkmcnt(0): global loads stay in flight across the
//    barrier (avoids __syncthreads' forced vmcnt(0) drain)
#define T1LD 40
__global__ __launch_bounds__(256) void gemm_t1(const float* __restrict__ A, const unsigned short* __restrict__ Bt,
                                               float* __restrict__ C) {
    __shared__ __align__(16) unsigned short As[2][64 * T1LD];
    __shared__ __align__(16) unsigned short Bs[2][128 * T1LD];
    const int Klim = 15000, Kpad = 15008;
    int bm0 = blockIdx.y * 64;
    int k0 = blockIdx.x * 480;
    int kend = k0 + 480; if (kend > Kpad) kend = Kpad;
    int tid = threadIdx.x;
    int w = tid >> 6, l = tid & 63, q = l >> 4, r = l & 15;
    int wr = w >> 1, wc = w & 1;

    floatx4 acc[2][4];
#pragma unroll
    for (int i = 0; i < 2; i++)
#pragma unroll
        for (int c = 0; c < 4; c++) acc[i][c] = (floatx4)0.0f;

    int mA = tid >> 2, kcA = (tid & 3) * 8;    // A: 64 rows, 4 thr/row, 8 floats each
    int nB = tid >> 1, kcB = (tid & 1) * 16;   // B: 128 rows, 2 thr/row, 16 shorts each
    const float* Ap0 = A + (size_t)(bm0 + mA) * (size_t)Klim;
    const unsigned short* Bp0 = Bt + (size_t)nB * (size_t)Kpad;

    float av[8];
    short8 bv0, bv1;

    // load tile at kt into registers
    auto loadT = [&](int kt) {
        const float* Ap = Ap0 + kt + kcA;
        if (kt + kcA + 8 <= Klim) {
#pragma unroll
            for (int j = 0; j < 4; j++) {
                float2 p = *(const float2*)(Ap + 2 * j);
                av[2 * j] = p.x; av[2 * j + 1] = p.y;
            }
        } else {
#pragma unroll
            for (int j = 0; j < 8; j++) av[j] = (kt + kcA + j < Klim) ? Ap[j] : 0.f;
        }
        bv0 = *(const short8*)(Bp0 + kt + kcB);
        bv1 = *(const short8*)(Bp0 + kt + kcB + 8);
    };

    loadT(k0);
    int cur = 0;
    for (int kt = k0; kt < kend; kt += 32, cur ^= 1) {
        // ds_write current tile from regs (compiler waits vmcnt only for these regs)
        short8 sa;
#pragma unroll
        for (int j = 0; j < 8; j++) sa[j] = (short)f2bf(av[j]);
        *(short8*)&As[cur][mA * T1LD + kcA] = sa;
        *(short8*)&Bs[cur][nB * T1LD + kcB] = bv0;
        *(short8*)&Bs[cur][nB * T1LD + kcB + 8] = bv1;
        // issue next-tile global loads -> they remain in flight across the barrier
        if (kt + 32 < kend) loadT(kt + 32);
        // drain only LDS ops, then raw barrier (no vmcnt drain)
        asm volatile("s_waitcnt lgkmcnt(0)" ::: "memory");
        __builtin_amdgcn_s_barrier();
        short8 a0 = *(const short8*)&As[cur][(wr * 32 + r) * T1LD + q * 8];
        short8 a1 = *(const short8*)&As[cur][(wr * 32 + 16 + r) * T1LD + q * 8];
        short8 b0 = *(const short8*)&Bs[cur][(wc * 64 + r) * T1LD + q * 8];
        short8 b1 = *(const short8*)&Bs[cur][(wc * 64 + 16 + r) * T1LD + q * 8];
        short8 b2 = *(const short8*)&Bs[cur][(wc * 64 + 32 + r) * T1LD + q * 8];
        short8 b3 = *(const short8*)&Bs[cur][(wc * 64 + 48 + r) * T1LD + q * 8];
        acc[0][0] = __builtin_amdgcn_mfma_f32_16x16x32_bf16(a0, b0, acc[0][0], 0, 0, 0);
        acc[0][1] = __builtin_amdgcn_mfma_f32_16x16x32_bf16(a0, b1, acc[0][1], 0, 0, 0);
        acc[0][2] = __builtin_amdgcn_mfma_f32_16x16x32_bf16(a0, b2, acc[0][2], 0, 0, 0);
        acc[0][3] = __builtin_amdgcn_mfma_f32_16x16x32_bf16(a0, b3, acc[0][3], 0, 0, 0);
        acc[1][0] = __builtin_amdgcn_mfma_f32_16x16x32_bf16(a1, b0, acc[1][0], 0, 0, 0);
        acc[1][1] = __builtin_amdgcn_mfma_f32_16x16x32_bf16(a1, b1, acc[1][1], 0, 0, 0);
        acc[1][2] = __builtin_amdgcn_mfma_f32_16x16x32_bf16(a1, b2, acc[1][2], 0, 0, 0);
        acc[1][3] = __builtin_amdgcn_mfma_f32_16x16x32_bf16(a1, b3, acc[1][3], 0, 0, 0);
        // no trailing barrier: double buffer + per-wave lgkmcnt(0) before next barrier
        // guarantees read_i retired before any write_{i+2} to the same buffer
    }

    // epilogue: C/D layout col=lane&15, row=(lane>>4)*4+reg; split-K atomic into xc
#pragma unroll
    for (int c = 0; c < 4; c++) {
        int col = wc * 64 + c * 16 + r;
#pragma unroll
        for (int i = 0; i < 2; i++) {
#pragma unroll
            for (int v = 0; v < 4; v++) {
                int row = bm0 + wr * 32 + i * 16 + q * 4 + v;
                atomicAdd(&C[(size_t)row * 384 + col], acc[i][c][v]);
            }
        }
    }
}

// ---------------- batched bf16 MFMA GEMM: Cz[M,N] = A[M,K] @ Bz[K,N], z = blockIdx.z ----------------
// OM: 1 = bf16 flat [row*ldc+col] per batch (stride sC); 2 = bf16 transposed-packed Vt[col*ldc + row*20 + z]
template <int OM>
__global__ __launch_bounds__(256) void gemm_mfma_batch(const float* __restrict__ A, const float* __restrict__ B,
                                                       void* __restrict__ Cv,
                                                       int M, int Nn, int K, int ldc,
                                                       long sB, long sC) {
    __shared__ __align__(16) unsigned short As[64 * LDST];
    __shared__ __align__(16) unsigned short Bs[64 * LDST];
    const float* Bm = B + (size_t)blockIdx.z * sB;
    unsigned short* C16 = (unsigned short*)Cv + (size_t)blockIdx.z * sC;
    int bn0 = blockIdx.x * 64;
    int bm0 = blockIdx.y * 64;
    int tid = threadIdx.x;
    int w = tid >> 6, l = tid & 63, q = l >> 4, r = l & 15;
    int wr = w >> 1, wc = w & 1;

    floatx4 acc[2][2];
#pragma unroll
    for (int i = 0; i < 2; i++)
#pragma unroll
        for (int c = 0; c < 2; c++) acc[i][c] = (floatx4)0.0f;

    int mA = tid >> 2, kcA = (tid & 3) * 8;
    int nB = tid >> 2, kcB = (tid & 3) * 8;
    int gmA = bm0 + mA;
    int gnB = bn0 + nB;

    for (int kt = 0; kt < K; kt += 32) {
        {
            float av[8];
            const float* Ap = A + (size_t)gmA * K + kt + kcA;
            if (gmA < M) {
#pragma unroll
                for (int j = 0; j < 4; j++) {
                    float2 p = *(const float2*)(Ap + j * 2);
                    av[j * 2] = p.x; av[j * 2 + 1] = p.y;
                }
            } else {
#pragma unroll
                for (int j = 0; j < 8; j++) av[j] = 0.f;
            }
            short8 sv;
#pragma unroll
            for (int j = 0; j < 8; j++) sv[j] = (short)f2bf(av[j]);
            *(short8*)&As[mA * LDST + kcA] = sv;
        }
        {
            short8 sv;
#pragma unroll
            for (int j = 0; j < 8; j++) {
                int gk = kt + kcB + j;
                float v = (gnB < Nn) ? Bm[(size_t)gk * Nn + gnB] : 0.f;
                sv[j] = (short)f2bf(v);
            }
            *(short8*)&Bs[nB * LDST + kcB] = sv;
        }
        __syncthreads();
        short8 a0 = *(const short8*)&As[(wr * 32 + r) * LDST + q * 8];
        short8 a1 = *(const short8*)&As[(wr * 32 + 16 + r) * LDST + q * 8];
        short8 b0 = *(const short8*)&Bs[(wc * 32 + r) * LDST + q * 8];
        short8 b1 = *(const short8*)&Bs[(wc * 32 + 16 + r) * LDST + q * 8];
        acc[0][0] = __builtin_amdgcn_mfma_f32_16x16x32_bf16(a0, b0, acc[0][0], 0, 0, 0);
        acc[0][1] = __builtin_amdgcn_mfma_f32_16x16x32_bf16(a0, b1, acc[0][1], 0, 0, 0);
        acc[1][0] = __builtin_amdgcn_mfma_f32_16x16x32_bf16(a1, b0, acc[1][0], 0, 0, 0);
        acc[1][1] = __builtin_amdgcn_mfma_f32_16x16x32_bf16(a1, b1, acc[1][1], 0, 0, 0);
        __syncthreads();
    }

#pragma unroll
    for (int c = 0; c < 2; c++) {
        int col = bn0 + wc * 32 + c * 16 + r;
        if (col >= Nn) continue;
#pragma unroll
        for (int i = 0; i < 2; i++) {
#pragma unroll
            for (int v = 0; v < 4; v++) {
                int row = bm0 + wr * 32 + i * 16 + q * 4 + v;
                if (row >= M) continue;
                if (OM == 1) C16[(size_t)row * ldc + col] = f2bf(acc[i][c][v]);
                else C16[(size_t)col * ldc + row * 20 + blockIdx.z] = f2bf(acc[i][c][v]);
            }
        }
    }
}

// fused reshape: W[32,750,8] -> Wr[750,256] for both conv weights
__global__ __launch_bounds__(256) void k_wcr_both(const float* __restrict__ Wc2, const float* __restrict__ Wc1,
                                                  float* __restrict__ Wc2r, float* __restrict__ Wc1r) {
    int cc = blockIdx.x, j = threadIdx.x;
    const float* W = (cc < 750) ? Wc2 : Wc1;
    float* Wr = (cc < 750) ? Wc2r : Wc1r;
    int c = (cc < 750) ? cc : cc - 750;
    Wr[(size_t)c * 256 + j] = W[(size_t)(j >> 3) * 6000 + c * 8 + (j & 7)];
}

// T[(v*256+o*8+k), j] = sum_l emb[v,l+k] * Wxt2[(o*121+l), j]
__global__ __launch_bounds__(128) void k_T_build(const float* __restrict__ emb, const float* __restrict__ Wxt2,
                                                 float* __restrict__ T) {
    __shared__ float el[128];
    int v = blockIdx.x >> 5, o = blockIdx.x & 31, j = threadIdx.x;
    el[j] = emb[(size_t)v * 128 + j];
    __syncthreads();
    float acc[8] = {};
    for (int l = 0; l < 121; l++) {
        float w = Wxt2[(size_t)(o * 121 + l) * 128 + j];
#pragma unroll
        for (int k = 0; k < 8; k++) acc[k] += el[l + k] * w;
    }
#pragma unroll
    for (int k = 0; k < 8; k++) T[(size_t)(v * 256 + o * 8 + k) * 128 + j] = acc[k];
}

// Bt[t*256 + o*8+k, j] = Wxt1[(o*13 + t-k)*128 + j] if 0<=t-k<13 else 0
__global__ __launch_bounds__(128) void k_bt_build(const float* __restrict__ Wxt1, float* __restrict__ Bt) {
    int ok = blockIdx.x, t = blockIdx.y, j = threadIdx.x;
    int o = ok >> 3, k = ok & 7, lpos = t - k;
    float v = (lpos >= 0 && lpos < 13) ? Wxt1[(size_t)(o * 13 + lpos) * 128 + j] : 0.f;
    Bt[(size_t)(t * 256 + ok) * 128 + j] = v;
}

// xt2[b,j] = b2v[j] + sum_c U16[c, t2[b,c], j]  -- bf16 U, short8 loads
__global__ __launch_bounds__(128) void k_u_gather16(const int* __restrict__ t2, const unsigned short* __restrict__ U,
                                                    const float* __restrict__ b2v, float* __restrict__ xc) {
    __shared__ int offs[752];
    __shared__ float red[8][128];
    int b = blockIdx.x, tid = threadIdx.x;
    int rg = tid >> 4, lane = tid & 15;
    const int* t2b = t2 + (size_t)b * 750;
    for (int i = tid; i < 750; i += 128) offs[i] = i * 3328 + t2b[i] * 128;
    __syncthreads();
    float a[8] = {};
#pragma unroll 4
    for (int i = rg; i < 750; i += 8) {
        short8 v = *(const short8*)&U[(size_t)offs[i] + lane * 8];
#pragma unroll
        for (int c = 0; c < 8; c++) a[c] += bf2f((unsigned short)v[c]);
    }
#pragma unroll
    for (int c = 0; c < 8; c++) red[rg][lane * 8 + c] = a[c];
    __syncthreads();
    float s = b2v[tid];
#pragma unroll
    for (int g = 0; g < 8; g++) s += red[g][tid];
    xc[(size_t)b * 384 + 256 + tid] = s;
}

// ---- conv-bias folds ----
__global__ void k_bias_init(const float* __restrict__ bxt1, const float* __restrict__ bxt2,
                            float* __restrict__ b1v, float* __restrict__ b2v) {
    int j = threadIdx.x;
    b1v[j] = bxt1[j];
    b2v[j] = bxt2[j];
}

// blocks 0-31: b1v += bc1[o]*colsum(Wxt1,o); blocks 32-63: b2v += bc2[o]*colsum(Wxt2,o)
__global__ __launch_bounds__(128) void k_bias_acc_both(const float* __restrict__ bc1, const float* __restrict__ Wxt1,
                                                       float* __restrict__ b1v,
                                                       const float* __restrict__ bc2, const float* __restrict__ Wxt2,
                                                       float* __restrict__ b2v) {
    int b = blockIdx.x, j = threadIdx.x;
    if (b < 32) {
        const float* p = Wxt1 + (size_t)b * 13 * 128 + j;
        float t = 0.f;
        for (int l = 0; l < 13; l++) t += p[(size_t)l * 128];
        atomicAdd(&b1v[j], bc1[b] * t);
    } else {
        int o = b - 32;
        const float* p = Wxt2 + (size_t)o * 121 * 128 + j;
        float t = 0.f;
        for (int l = 0; l < 121; l++) t += p[(size_t)l * 128];
        atomicAdd(&b2v[j], bc2[o] * t);
    }
}

// one-shot bias init: xc[:,0:128]=bg2, xc[:,128:256]=b1v, f2=bf2
__global__ __launch_bounds__(768) void k_initC(float* __restrict__ xc, float* __restrict__ f2,
                                               const float* __restrict__ bg2, const float* __restrict__ b1v,
                                               const float* __restrict__ bf2) {
    int b = blockIdx.x, t = threadIdx.x;
    if (t < 128) xc[(size_t)b * 384 + t] = bg2[t];
    else if (t < 256) xc[(size_t)b * 384 + t] = b1v[t - 128];
    else f2[(size_t)b * 512 + t - 256] = bf2[t - 256];
}

// out[b] = sum_j relu(f2[b,j]) * Wo[j] + bo
__global__ __launch_bounds__(64) void k_final(const float* __restrict__ f2, const float* __restrict__ Wo,
                                              const float* __restrict__ bo, float* __restrict__ out) {
    int b = blockIdx.x, lane = threadIdx.x;
    float s = 0.f;
    for (int j = lane; j < 512; j += 64) s += fmaxf(f2[(size_t)b * 512 + j], 0.f) * Wo[j];
    for (int off = 32; off; off >>= 1) s += __shfl_down(s, off);
    if (lane == 0) out[b] = s + bo[0];
}

extern "C" void kernel_launch(void* const* d_in, const int* in_sizes, int n_in,
                              void* d_out, int out_size, void* d_ws, size_t ws_size,
                              hipStream_t stream) {
    const float* x    = (const float*)d_in[0];
    const int*   ei   = (const int*)d_in[1];
    const float* t1   = (const float*)d_in[3];
    const int*   t2   = (const int*)d_in[4];
    const float* W1   = (const float*)d_in[5];
    const float* b1   = (const float*)d_in[6];
    const float* W2   = (const float*)d_in[7];
    const float* b2   = (const float*)d_in[8];
    const float* W3   = (const float*)d_in[9];
    const float* b3   = (const float*)d_in[10];
    const float* Wg1  = (const float*)d_in[11];
    const float* bg1  = (const float*)d_in[12];
    const float* Wg2  = (const float*)d_in[13];
    const float* bg2  = (const float*)d_in[14];
    const float* emb  = (const float*)d_in[15];
    const float* Wc2  = (const float*)d_in[16];
    const float* bc2  = (const float*)d_in[17];
    const float* Wxt2 = (const float*)d_in[18];
    const float* bxt2 = (const float*)d_in[19];
    const float* Wc1  = (const float*)d_in[20];
    const float* bc1  = (const float*)d_in[21];
    const float* Wxt1 = (const float*)d_in[22];
    const float* bxt1 = (const float*)d_in[23];
    const float* Wf1  = (const float*)d_in[24];
    const float* bf1  = (const float*)d_in[25];
    const float* Wf2  = (const float*)d_in[26];
    const float* bf2  = (const float*)d_in[27];
    const float* Wo   = (const float*)d_in[28];
    const float* bo   = (const float*)d_in[29];
    float* out = (float*)d_out;

    float* ws = (float*)d_ws;
    float* dinv  = ws + o_dinv;
    unsigned short* g312b = (unsigned short*)(ws + o_g312);   // 1024 x 320 bf16
    unsigned short* g1024b = (unsigned short*)(ws + o_g1024); // 1024 x 1024 bf16
    float* xc    = ws + o_xc;     // [1024 x 384] fp32
    unsigned short* f1b = (unsigned short*)(ws + o_f1);       // 1024 x 1024 bf16
    float* f2    = ws + o_f2;
    float* b1v   = ws + o_b1v;
    float* b2v   = ws + o_b2v;
    int* csrOff  = (int*)(ws + o_iws);
    int* csrCur  = csrOff + (NN + 1);
    int* csrSrc  = csrCur + NN;
    int* blockSum = (int*)(ws + o_f1 + 600000);  // scratch, dead before f1b written
    int* blockOff = blockSum + 40;
    float* bufA  = ws + o_bufA;
    float* bufB  = ws + o_bufB;
    float* T    = bufA;
    unsigned short* U16  = (unsigned short*)(bufA + 851968);
    unsigned short* Vt16 = (unsigned short*)(bufA + 2200000);  // 128 x 15008 bf16
    unsigned short* Wt   = (unsigned short*)(bufA + 3200000);  // transposed weights
    float* Wc2r = bufA + 4000000;
    float* Wc1r = bufA + 4200000;
    float* Btb  = bufA + 4400000;
    // bf16 node pipeline (inside bufB)
    unsigned* aggb = (unsigned*)bufB;                          // NN*80 uints max
    unsigned short* h16 = (unsigned short*)(bufB + 5500000);   // up to NN*312

    unsigned short* W1t  = Wt + 0;
    unsigned short* W2t  = Wt + 12288;
    unsigned short* W3t  = Wt + 30720;
    unsigned short* Wg1t = Wt + 81920;
    unsigned short* Wg2t = Wt + 409600;
    unsigned short* Wf1t = Wt + 540672;
    unsigned short* Wf2t = Wt + 933888;

    // ---- CSR build + degree + weight converts ----
    hipMemsetAsync(csrCur, 0, NN * sizeof(int), stream);
    k_hist<<<NE / 256, 256, 0, stream>>>(ei + NE, csrCur);
    k_scan1<<<40, 1024, 0, stream>>>(csrCur, csrOff, blockSum, dinv);
    k_scan2<<<1, 64, 0, stream>>>(blockSum, blockOff);
    k_scan3<<<40, 1024, 0, stream>>>(csrOff, csrCur, blockOff);
    k_fill<<<NE / 256, 256, 0, stream>>>(ei, csrCur, csrSrc);
    k_cvt_wt<<<3328, 256, 0, stream>>>(W1, W2, W3, Wg1, Wg2, Wf1, Wf2, Wt);

    // ---- GCN layers: bf16 pipeline, aggregate input (2-wide), GEMM(bias+relu) ----
    k_agg_x<<<NN, 64, 0, stream>>>(x, dinv, csrOff, csrSrc, aggb);
    gemm_bt<true, true, false, true><<<dim3(2, 640, 1), 256, 0, stream>>>(
        aggb, W1t, b1, h16, 78, 96, 96, 96, 96, 96, 96, 96);
    k_agg16<<<NN, 64, 0, stream>>>((unsigned*)h16, dinv, csrOff, csrSrc, aggb, 48);
    gemm_bt<true, true, false, true><<<dim3(3, 640, 1), 256, 0, stream>>>(
        aggb, W2t, b2, h16, 156, 160, 96, 96, 96, 96, 160, 96);
    k_agg16<<<NN, 128, 0, stream>>>((unsigned*)h16, dinv, csrOff, csrSrc, aggb, 80);
    gemm_bt<true, true, false, true><<<dim3(5, 640, 1), 256, 0, stream>>>(
        aggb, W3t, b3, h16, 312, 312, 160, 160, 160, 160, 312, 160);
    k_segmax16<<<NB, 320, 0, stream>>>(h16, g312b);
    gemm_bt<true, true, false, true><<<dim3(16, 16, 1), 256, 0, stream>>>(
        g312b, Wg1t, bg1, g1024b, 1024, 1024, 320, 320, 320, 320, 1024, 320);

    // fused conv biases, then one-shot C-inits
    k_bias_init<<<1, 128, 0, stream>>>(bxt1, bxt2, b1v, b2v);
    k_bias_acc_both<<<64, 128, 0, stream>>>(bc1, Wxt1, b1v, bc2, Wxt2, b2v);
    k_initC<<<NB, 768, 0, stream>>>(xc, f2, bg2, b1v, bf2);

    // xc[:,0:128] = g1024 @ Wg2 + bg2   (split-K atomic)
    gemm_bt<true, false, true, false><<<dim3(2, 16, 8), 256, 0, stream>>>(
        g1024b, Wg2t, nullptr, xc + 0, 128, 128, 1024, 1024, 1024, 1024, 384, 128);

    // ---- protein branch 2: U16 = Wc2r @ T (26-batch, bf16 out), then vector gather-sum ----
    k_wcr_both<<<1500, 256, 0, stream>>>(Wc2, Wc1, Wc2r, Wc1r);
    k_T_build<<<26 * 32, 128, 0, stream>>>(emb, Wxt2, T);
    gemm_mfma_batch<1><<<dim3(2, 12, 26), 256, 0, stream>>>(Wc2r, T, U16, 750, 128, 256, 3328, 32768, 128);
    k_u_gather16<<<NB, 128, 0, stream>>>(t2, U16, b2v, xc);

    // ---- protein branch 1: Vt16 = (Wc1r @ Bt)^T packed (20-batch), then xc[:,128:256] = t1 @ Vt^T ----
    k_bt_build<<<dim3(256, 20), 128, 0, stream>>>(Wxt1, Btb);
    hipMemsetAsync(Vt16, 0, (size_t)128 * 15008 * 2, stream);
    gemm_mfma_batch<2><<<dim3(2, 12, 20), 256, 0, stream>>>(Wc1r, Btb, Vt16, 750, 128, 256, 15008, 32768, 0);
    gemm_t1<<<dim3(32, 16, 1), 256, 0, stream>>>(t1, Vt16, xc + 128);

    // ---- head ----
    gemm_bt<false, true, false, true><<<dim3(16, 16, 1), 256, 0, stream>>>(
        xc, Wf1t, bf1, f1b, 1024, 1024, 384, 384, 384, 384, 1024, 384);
    gemm_bt<true, false, true, false><<<dim3(8, 16, 4), 256, 0, stream>>>(
        f1b, Wf2t, nullptr, f2, 512, 512, 1024, 1024, 1024, 1024, 512, 256);
    k_final<<<NB, 64, 0, stream>>>(f2, Wo, bo, out);
}

// Round 2
// 458.432 us; speedup vs baseline: 1.0157x; 1.0040x over previous
//
#include <hip/hip_runtime.h>
#include <hip/hip_bf16.h>

// Problem constants
#define NN 40960      // nodes
#define NE 163840     // edges
#define NB 1024       // graphs

typedef __attribute__((ext_vector_type(8))) short short8;
typedef __attribute__((ext_vector_type(4))) float floatx4;

__device__ inline unsigned short f2bf(float f) {
    union { float f; unsigned u; } v; v.f = f;
    unsigned r = v.u + 0x7fffu + ((v.u >> 16) & 1u);
    return (unsigned short)(r >> 16);
}
__device__ inline float bf2f(unsigned short s) {
    union { unsigned u; float f; } v; v.u = ((unsigned)s) << 16; return v.f;
}
__device__ inline unsigned pack2bf(float lo, float hi) {
    return (unsigned)f2bf(lo) | ((unsigned)f2bf(hi) << 16);
}

// ---------------- workspace layout (float elements) ----------------
static const size_t o_dinv = 0, o_g312 = 40960, o_g1024 = 360448, o_xc = 1409024,
                    o_f1 = 1802240, o_f2 = 2850816, o_b1v = 3375104, o_b2v = 3375232,
                    o_iws = 3375360, o_bufA = 3621124, o_bufB = 16400644;
// bufA: T @0 | U16 @+851968 (bf16) | Vt16 @+2200000 (128x15360 bf16)
//       | Wt @+3200000 (transposed bf16 weights) | Wc2r @+4000000 | Wc1r @+4200000 | Btb @+4400000
// bufB: aggb @0 (NN*160 shorts max) | h16 @5.5M ; after segmax both dead ->
//       P (t1 split-K partials, 48*1024*128 fp32 = 6.3M floats) overlays bufB @0

// ---------------- CSR build ----------------
__global__ void k_hist(const int* __restrict__ dst, int* __restrict__ cnt) {
    int e = blockIdx.x * 256 + threadIdx.x;
    if (e < NE) atomicAdd(&cnt[dst[e]], 1);
}

__global__ __launch_bounds__(1024) void k_scan1(const int* __restrict__ cnt, int* __restrict__ offTmp,
                                                int* __restrict__ blockSum, float* __restrict__ dinv) {
    __shared__ int lds[1024];
    int tid = threadIdx.x;
    int i = blockIdx.x * 1024 + tid;
    int v = cnt[i];
    dinv[i] = rsqrtf((float)v + 1.0f);  // deg = in-count + self loop
    lds[tid] = v;
    __syncthreads();
    for (int s = 1; s < 1024; s <<= 1) {
        int t = (tid >= s) ? lds[tid - s] : 0;
        __syncthreads();
        lds[tid] += t;
        __syncthreads();
    }
    offTmp[i] = lds[tid] - v;  // local exclusive
    if (tid == 1023) blockSum[blockIdx.x] = lds[1023];
}

__global__ __launch_bounds__(64) void k_scan2(const int* __restrict__ blockSum, int* __restrict__ blockOff) {
    int l = threadIdx.x;
    int s = (l < 40) ? blockSum[l] : 0;
    int orig = s;
    for (int d = 1; d < 64; d <<= 1) {
        int t = __shfl_up(s, d);
        if (l >= d) s += t;
    }
    if (l < 40) blockOff[l] = s - orig;
}

__global__ __launch_bounds__(1024) void k_scan3(int* __restrict__ off, int* __restrict__ cur,
                                                const int* __restrict__ blockOff) {
    int i = blockIdx.x * 1024 + threadIdx.x;
    int o = off[i] + blockOff[blockIdx.x];
    off[i] = o;
    cur[i] = o;
    if (i == NN - 1) off[NN] = NE;
}

__global__ void k_fill(const int* __restrict__ ei, int* __restrict__ cur, int* __restrict__ srcOut) {
    int e = blockIdx.x * 256 + threadIdx.x;
    if (e >= NE) return;
    int s = ei[e], d = ei[NE + e];
    int pos = atomicAdd(&cur[d], 1);
    srcOut[pos] = s;
}

// ---------------- fused weight transpose-convert: all 7 weights -> padded bf16 [N64, Kpad] ----
__global__ __launch_bounds__(256) void k_cvt_wt(const float* __restrict__ W1, const float* __restrict__ W2,
                                                const float* __restrict__ W3, const float* __restrict__ Wg1,
                                                const float* __restrict__ Wg2, const float* __restrict__ Wf1,
                                                const float* __restrict__ Wf2, unsigned short* __restrict__ dst) {
    const int cum[8]  = {0, 128, 320, 640, 1664, 1792, 2816, 3328};
    const int KP[7]   = {96, 96, 160, 320, 1024, 384, 1024};
    const int KB[7]   = {78, 78, 156, 312, 1024, 384, 1024};
    const int NNm[7]  = {78, 156, 312, 1024, 128, 1024, 512};
    const size_t OFF[7] = {0, 12288, 30720, 81920, 409600, 540672, 933888};
    int m = 0;
    int bx = blockIdx.x;
    while (m < 6 && bx >= cum[m + 1]) m++;
    int r = bx - cum[m];
    const float* src = (m == 0) ? W1 : (m == 1) ? W2 : (m == 2) ? W3 : (m == 3) ? Wg1
                     : (m == 4) ? Wg2 : (m == 5) ? Wf1 : Wf2;
    int kp = KP[m], kb = KB[m], nn = NNm[m];
    unsigned short* d = dst + OFF[m] + (size_t)r * kp;
    for (int k = threadIdx.x; k < kp; k += 256) {
        float v = (r < nn && k < kb) ? src[(size_t)k * nn + r] : 0.f;
        d[k] = f2bf(v);
    }
}

// ---------------- GCN aggregation, layer 1: fp32 x in, bf16 out padded to 96. 2 cols/thread ----
__global__ __launch_bounds__(64) void k_agg_x(const float* __restrict__ x, const float* __restrict__ dinv,
                                              const int* __restrict__ off, const int* __restrict__ srcs,
                                              unsigned* __restrict__ out) {
    int n = blockIdx.x;
    int f = threadIdx.x;          // uint column (2 floats)
    if (f >= 48) return;
    if (f >= 39) { out[(size_t)n * 48 + f] = 0; return; }
    float di = dinv[n];
    float2 sv = *(const float2*)&x[(size_t)n * 78 + 2 * f];
    float a0 = sv.x * di * di, a1 = sv.y * di * di;
    int e0 = off[n], e1 = off[n + 1];
    int e = e0;
    for (; e + 4 <= e1; e += 4) {
        int s0 = srcs[e], s1 = srcs[e + 1], s2 = srcs[e + 2], s3 = srcs[e + 3];
        float d0 = dinv[s0] * di, d1 = dinv[s1] * di, d2 = dinv[s2] * di, d3 = dinv[s3] * di;
        float2 v0 = *(const float2*)&x[(size_t)s0 * 78 + 2 * f];
        float2 v1 = *(const float2*)&x[(size_t)s1 * 78 + 2 * f];
        float2 v2 = *(const float2*)&x[(size_t)s2 * 78 + 2 * f];
        float2 v3 = *(const float2*)&x[(size_t)s3 * 78 + 2 * f];
        a0 += v0.x * d0 + v1.x * d1 + v2.x * d2 + v3.x * d3;
        a1 += v0.y * d0 + v1.y * d1 + v2.y * d2 + v3.y * d3;
    }
    for (; e < e1; e++) {
        int s = srcs[e];
        float dd = dinv[s] * di;
        float2 v = *(const float2*)&x[(size_t)s * 78 + 2 * f];
        a0 += v.x * dd; a1 += v.y * dd;
    }
    out[(size_t)n * 48 + f] = pack2bf(a0, a1);
}

// ---------------- GCN aggregation bf16 in/out, 2 cols/thread (F2 = F/2 uints per row) ----------------
__global__ void k_agg16(const unsigned* __restrict__ h, const float* __restrict__ dinv,
                        const int* __restrict__ off, const int* __restrict__ srcs,
                        unsigned* __restrict__ out, int F2) {
    int n = blockIdx.x;
    int f = threadIdx.x;
    if (f >= F2) return;
    float di = dinv[n];
    unsigned s0v = h[(size_t)n * F2 + f];
    float a0 = bf2f((unsigned short)(s0v & 0xffff)) * di * di;
    float a1 = bf2f((unsigned short)(s0v >> 16)) * di * di;
    int e0 = off[n], e1 = off[n + 1];
    int e = e0;
    for (; e + 4 <= e1; e += 4) {
        int s0 = srcs[e], s1 = srcs[e + 1], s2 = srcs[e + 2], s3 = srcs[e + 3];
        float d0 = dinv[s0] * di, d1 = dinv[s1] * di, d2 = dinv[s2] * di, d3 = dinv[s3] * di;
        unsigned v0 = h[(size_t)s0 * F2 + f];
        unsigned v1 = h[(size_t)s1 * F2 + f];
        unsigned v2 = h[(size_t)s2 * F2 + f];
        unsigned v3 = h[(size_t)s3 * F2 + f];
        a0 += bf2f((unsigned short)(v0 & 0xffff)) * d0 + bf2f((unsigned short)(v1 & 0xffff)) * d1
            + bf2f((unsigned short)(v2 & 0xffff)) * d2 + bf2f((unsigned short)(v3 & 0xffff)) * d3;
        a1 += bf2f((unsigned short)(v0 >> 16)) * d0 + bf2f((unsigned short)(v1 >> 16)) * d1
            + bf2f((unsigned short)(v2 >> 16)) * d2 + bf2f((unsigned short)(v3 >> 16)) * d3;
    }
    for (; e < e1; e++) {
        int s = srcs[e];
        float dd = dinv[s] * di;
        unsigned v = h[(size_t)s * F2 + f];
        a0 += bf2f((unsigned short)(v & 0xffff)) * dd;
        a1 += bf2f((unsigned short)(v >> 16)) * dd;
    }
    out[(size_t)n * F2 + f] = pack2bf(a0, a1);
}

// segment max over 40 consecutive nodes per graph; bf16 in (already relu'd), bf16 out padded to 320
__global__ void k_segmax16(const unsigned short* __restrict__ h, unsigned short* __restrict__ g) {
    int gr = blockIdx.x, f = threadIdx.x;
    if (f >= 320) return;
    if (f >= 312) { g[(size_t)gr * 320 + f] = 0; return; }
    float m = 0.0f;
    const unsigned short* base = h + (size_t)gr * 40 * 312 + f;
    for (int i = 0; i < 40; i++) m = fmaxf(m, bf2f(base[(size_t)i * 312]));
    g[(size_t)gr * 320 + f] = f2bf(m);
}

// ---------------- bf16 MFMA GEMM with transposed-bf16 B: C = A @ Bt^T ----------------
// A: bf16 [M,lda] (ABF16, zero-padded K) or fp32 [M,lda] with Klim valid columns.
// Bt: bf16 [>=gridX*64 rows, ldb] zero-padded. M multiple of 64. Kpad multiple of 32.
#define LDST 72
template <bool ABF16, bool OUTBF16, bool ATOMIC, bool RELU_OUT>
__global__ __launch_bounds__(256) void gemm_bt(const void* __restrict__ Av, const unsigned short* __restrict__ Bt,
                                               const float* __restrict__ bias, void* __restrict__ Cv,
                                               int Nn, int Npad, int Kpad, int Klim,
                                               int lda, int ldb, int ldc, int ksplit) {
    __shared__ __align__(16) unsigned short As[64 * LDST];
    __shared__ __align__(16) unsigned short Bs[64 * LDST];
    const float* Af = (const float*)Av;
    const unsigned short* A16 = (const unsigned short*)Av;
    float* Cf = (float*)Cv;
    unsigned short* C16 = (unsigned short*)Cv;
    int bn0 = blockIdx.x * 64;
    int bm0 = blockIdx.y * 64;
    int k0 = blockIdx.z * ksplit;
    int kend = k0 + ksplit; if (kend > Kpad) kend = Kpad;
    int tid = threadIdx.x;
    int w = tid >> 6, l = tid & 63, q = l >> 4, r = l & 15;
    int wr = w >> 1, wc = w & 1;

    floatx4 acc[2][2];
#pragma unroll
    for (int i = 0; i < 2; i++)
#pragma unroll
        for (int c = 0; c < 2; c++) acc[i][c] = (floatx4)0.0f;

    int mA = tid >> 2, kcA = (tid & 3) * 8;
    int nB = tid >> 2, kcB = (tid & 3) * 8;
    int gmA = bm0 + mA;
    int gnB = bn0 + nB;

    for (int kt = k0; kt < kend; kt += 32) {
        // ---- stage A ----
        if (ABF16) {
            *(short8*)&As[mA * LDST + kcA] = *(const short8*)(A16 + (size_t)gmA * lda + kt + kcA);
        } else {
            const float* Ap = Af + (size_t)gmA * lda + kt + kcA;
            float av[8];
            if (kt + kcA + 8 <= Klim) {
#pragma unroll
                for (int j = 0; j < 4; j++) {
                    float2 p = *(const float2*)(Ap + j * 2);
                    av[j * 2] = p.x; av[j * 2 + 1] = p.y;
                }
            } else {
#pragma unroll
                for (int j = 0; j < 8; j++) av[j] = (kt + kcA + j < Klim) ? Ap[j] : 0.f;
            }
            short8 sv;
#pragma unroll
            for (int j = 0; j < 8; j++) sv[j] = (short)f2bf(av[j]);
            *(short8*)&As[mA * LDST + kcA] = sv;
        }
        // ---- stage B: single short8 from transposed bf16 ----
        *(short8*)&Bs[nB * LDST + kcB] = *(const short8*)(Bt + (size_t)gnB * ldb + kt + kcB);
        __syncthreads();
        short8 a0 = *(const short8*)&As[(wr * 32 + r) * LDST + q * 8];
        short8 a1 = *(const short8*)&As[(wr * 32 + 16 + r) * LDST + q * 8];
        short8 b0 = *(const short8*)&Bs[(wc * 32 + r) * LDST + q * 8];
        short8 b1 = *(const short8*)&Bs[(wc * 32 + 16 + r) * LDST + q * 8];
        acc[0][0] = __builtin_amdgcn_mfma_f32_16x16x32_bf16(a0, b0, acc[0][0], 0, 0, 0);
        acc[0][1] = __builtin_amdgcn_mfma_f32_16x16x32_bf16(a0, b1, acc[0][1], 0, 0, 0);
        acc[1][0] = __builtin_amdgcn_mfma_f32_16x16x32_bf16(a1, b0, acc[1][0], 0, 0, 0);
        acc[1][1] = __builtin_amdgcn_mfma_f32_16x16x32_bf16(a1, b1, acc[1][1], 0, 0, 0);
        __syncthreads();
    }

    // ---- epilogue: C/D layout col=lane&15, row=(lane>>4)*4+reg ----
#pragma unroll
    for (int c2 = 0; c2 < 2; c2++) {
        int col = bn0 + wc * 32 + c2 * 16 + r;
        if (col >= Npad) continue;
        bool live = col < Nn;
        float bv = (bias && live) ? bias[col] : 0.f;
#pragma unroll
        for (int i = 0; i < 2; i++) {
#pragma unroll
            for (int v = 0; v < 4; v++) {
                int row = bm0 + wr * 32 + i * 16 + q * 4 + v;
                float val = live ? (acc[i][c2][v] + bv) : 0.f;
                if (RELU_OUT) val = fmaxf(val, 0.f);
                if (OUTBF16) {
                    C16[(size_t)row * ldc + col] = live ? f2bf(val) : (unsigned short)0;
                } else if (live) {
                    if (ATOMIC) atomicAdd(&Cf[(size_t)row * ldc + col], val);
                    else Cf[(size_t)row * ldc + col] = val;
                }
            }
        }
    }
}

// ---------------- dedicated t1 GEMM: P[ks][1024][128] = A[1024,15000]fp32 @ Vt16[128,15360]bf16^T ----
// Latency-optimized streaming split-K GEMM, NO atomics:
//  - tile 64(M) x 128(N); K padded to 15360, 48 splits x 320 (10 iters, even)
//  - double-buffered LDS, depth-2 register prefetch (two named register sets)
//  - RAW s_barrier + explicit lgkmcnt(0): global loads stay in flight across barriers
//  - partial tiles stored plain (coalesced) to P; k_red_t1 reduces into xc
#define T1LD 40
#define T1S  48
#define T1K  320
__global__ __launch_bounds__(256) void gemm_t1(const float* __restrict__ A, const unsigned short* __restrict__ Bt,
                                               float* __restrict__ P) {
    __shared__ __align__(16) unsigned short As[2][64 * T1LD];
    __shared__ __align__(16) unsigned short Bs[2][128 * T1LD];
    const int Klim = 15000;
    int bm0 = blockIdx.y * 64;
    int k0 = blockIdx.x * T1K;
    int tid = threadIdx.x;
    int w = tid >> 6, l = tid & 63, q = l >> 4, r = l & 15;
    int wr = w >> 1, wc = w & 1;

    floatx4 acc[2][4];
#pragma unroll
    for (int i = 0; i < 2; i++)
#pragma unroll
        for (int c = 0; c < 4; c++) acc[i][c] = (floatx4)0.0f;

    int mA = tid >> 2, kcA = (tid & 3) * 8;    // A: 64 rows, 4 thr/row, 8 floats each
    int nB = tid >> 1, kcB = (tid & 1) * 16;   // B: 128 rows, 2 thr/row, 16 shorts each
    const float* Ap0 = A + (size_t)(bm0 + mA) * (size_t)Klim + kcA;
    const unsigned short* Bp0 = Bt + (size_t)nB * 15360 + kcB;

    float4 a0A, a1A, a0B, a1B;
    short8 b0A, b1A, b0B, b1B;

    auto loadT = [&](int kt, float4& x0, float4& x1, short8& y0, short8& y1) {
        int col = kt + kcA;
        if (col + 8 <= Klim) {
            x0 = *(const float4*)(Ap0 + kt);
            x1 = *(const float4*)(Ap0 + kt + 4);
        } else {
            float t[8];
#pragma unroll
            for (int j = 0; j < 8; j++) t[j] = (col + j < Klim) ? Ap0[kt + j] : 0.f;
            x0 = make_float4(t[0], t[1], t[2], t[3]);
            x1 = make_float4(t[4], t[5], t[6], t[7]);
        }
        y0 = *(const short8*)(Bp0 + kt);
        y1 = *(const short8*)(Bp0 + kt + 8);
    };
    auto stageW = [&](int buf, const float4& x0, const float4& x1, const short8& y0, const short8& y1) {
        short8 sa;
        sa[0] = (short)f2bf(x0.x); sa[1] = (short)f2bf(x0.y); sa[2] = (short)f2bf(x0.z); sa[3] = (short)f2bf(x0.w);
        sa[4] = (short)f2bf(x1.x); sa[5] = (short)f2bf(x1.y); sa[6] = (short)f2bf(x1.z); sa[7] = (short)f2bf(x1.w);
        *(short8*)&As[buf][mA * T1LD + kcA] = sa;
        *(short8*)&Bs[buf][nB * T1LD + kcB] = y0;
        *(short8*)&Bs[buf][nB * T1LD + kcB + 8] = y1;
    };
    auto compute = [&](int buf) {
        short8 a0 = *(const short8*)&As[buf][(wr * 32 + r) * T1LD + q * 8];
        short8 a1 = *(const short8*)&As[buf][(wr * 32 + 16 + r) * T1LD + q * 8];
        short8 b0 = *(const short8*)&Bs[buf][(wc * 64 + r) * T1LD + q * 8];
        short8 b1 = *(const short8*)&Bs[buf][(wc * 64 + 16 + r) * T1LD + q * 8];
        short8 b2 = *(const short8*)&Bs[buf][(wc * 64 + 32 + r) * T1LD + q * 8];
        short8 b3 = *(const short8*)&Bs[buf][(wc * 64 + 48 + r) * T1LD + q * 8];
        acc[0][0] = __builtin_amdgcn_mfma_f32_16x16x32_bf16(a0, b0, acc[0][0], 0, 0, 0);
        acc[0][1] = __builtin_amdgcn_mfma_f32_16x16x32_bf16(a0, b1, acc[0][1], 0, 0, 0);
        acc[0][2] = __builtin_amdgcn_mfma_f32_16x16x32_bf16(a0, b2, acc[0][2], 0, 0, 0);
        acc[0][3] = __builtin_amdgcn_mfma_f32_16x16x32_bf16(a0, b3, acc[0][3], 0, 0, 0);
        acc[1][0] = __builtin_amdgcn_mfma_f32_16x16x32_bf16(a1, b0, acc[1][0], 0, 0, 0);
        acc[1][1] = __builtin_amdgcn_mfma_f32_16x16x32_bf16(a1, b1, acc[1][1], 0, 0, 0);
        acc[1][2] = __builtin_amdgcn_mfma_f32_16x16x32_bf16(a1, b2, acc[1][2], 0, 0, 0);
        acc[1][3] = __builtin_amdgcn_mfma_f32_16x16x32_bf16(a1, b3, acc[1][3], 0, 0, 0);
    };

    // depth-2 prefetch pipeline: regs consumed at phase i were loaded at phase i-2
    loadT(k0, a0A, a1A, b0A, b1A);
    loadT(k0 + 32, a0B, a1B, b0B, b1B);
#pragma unroll
    for (int it = 0; it < T1K / 32; it += 2) {
        // phase A (buffer 0, regset A)
        stageW(0, a0A, a1A, b0A, b1A);
        if (it + 2 < T1K / 32) loadT(k0 + (it + 2) * 32, a0A, a1A, b0A, b1A);
        asm volatile("s_waitcnt lgkmcnt(0)" ::: "memory");
        __builtin_amdgcn_s_barrier();
        asm volatile("" ::: "memory");
        compute(0);
        // phase B (buffer 1, regset B)
        stageW(1, a0B, a1B, b0B, b1B);
        if (it + 3 < T1K / 32) loadT(k0 + (it + 3) * 32, a0B, a1B, b0B, b1B);
        asm volatile("s_waitcnt lgkmcnt(0)" ::: "memory");
        __builtin_amdgcn_s_barrier();
        asm volatile("" ::: "memory");
        compute(1);
        // no trailing barrier: 2 buffers + per-wave lgkmcnt(0) before the next barrier
        // guarantee read_i retired before any write_{i+2} to the same buffer
    }

    // epilogue: plain coalesced stores of the partial tile (no atomics)
    float* Pp = P + (size_t)blockIdx.x * (1024 * 128) + (size_t)bm0 * 128;
#pragma unroll
    for (int c = 0; c < 4; c++) {
        int col = wc * 64 + c * 16 + r;
#pragma unroll
        for (int i = 0; i < 2; i++) {
#pragma unroll
            for (int v = 0; v < 4; v++) {
                int row = wr * 32 + i * 16 + q * 4 + v;
                Pp[(size_t)row * 128 + col] = acc[i][c][v];
            }
        }
    }
}

// reduce the 48 split-K partials into xc[:,128:256] (+= keeps the b1v init)
__global__ __launch_bounds__(128) void k_red_t1(const float* __restrict__ P, float* __restrict__ xc) {
    int row = blockIdx.x, j = threadIdx.x;
    const float* p = P + (size_t)row * 128 + j;
    float s = 0.f;
#pragma unroll
    for (int ks = 0; ks < T1S; ks++) s += p[(size_t)ks * (1024 * 128)];
    xc[(size_t)row * 384 + 128 + j] += s;
}

// ---------------- batched bf16 MFMA GEMM: Cz[M,N] = A[M,K] @ Bz[K,N], z = blockIdx.z ----------------
// OM: 1 = bf16 flat [row*ldc+col] per batch (stride sC); 2 = bf16 transposed-packed Vt[col*ldc + row*20 + z]
template <int OM>
__global__ __launch_bounds__(256) void gemm_mfma_batch(const float* __restrict__ A, const float* __restrict__ B,
                                                       void* __restrict__ Cv,
                                                       int M, int Nn, int K, int ldc,
                                                       long sB, long sC) {
    __shared__ __align__(16) unsigned short As[64 * LDST];
    __shared__ __align__(16) unsigned short Bs[64 * LDST];
    const float* Bm = B + (size_t)blockIdx.z * sB;
    unsigned short* C16 = (unsigned short*)Cv + (size_t)blockIdx.z * sC;
    int bn0 = blockIdx.x * 64;
    int bm0 = blockIdx.y * 64;
    int tid = threadIdx.x;
    int w = tid >> 6, l = tid & 63, q = l >> 4, r = l & 15;
    int wr = w >> 1, wc = w & 1;

    floatx4 acc[2][2];
#pragma unroll
    for (int i = 0; i < 2; i++)
#pragma unroll
        for (int c = 0; c < 2; c++) acc[i][c] = (floatx4)0.0f;

    int mA = tid >> 2, kcA = (tid & 3) * 8;
    int nB = tid >> 2, kcB = (tid & 3) * 8;
    int gmA = bm0 + mA;
    int gnB = bn0 + nB;

    for (int kt = 0; kt < K; kt += 32) {
        {
            float av[8];
            const float* Ap = A + (size_t)gmA * K + kt + kcA;
            if (gmA < M) {
#pragma unroll
                for (int j = 0; j < 4; j++) {
                    float2 p = *(const float2*)(Ap + j * 2);
                    av[j * 2] = p.x; av[j * 2 + 1] = p.y;
                }
            } else {
#pragma unroll
                for (int j = 0; j < 8; j++) av[j] = 0.f;
            }
            short8 sv;
#pragma unroll
            for (int j = 0; j < 8; j++) sv[j] = (short)f2bf(av[j]);
            *(short8*)&As[mA * LDST + kcA] = sv;
        }
        {
            short8 sv;
#pragma unroll
            for (int j = 0; j < 8; j++) {
                int gk = kt + kcB + j;
                float v = (gnB < Nn) ? Bm[(size_t)gk * Nn + gnB] : 0.f;
                sv[j] = (short)f2bf(v);
            }
            *(short8*)&Bs[nB * LDST + kcB] = sv;
        }
        __syncthreads();
        short8 a0 = *(const short8*)&As[(wr * 32 + r) * LDST + q * 8];
        short8 a1 = *(const short8*)&As[(wr * 32 + 16 + r) * LDST + q * 8];
        short8 b0 = *(const short8*)&Bs[(wc * 32 + r) * LDST + q * 8];
        short8 b1 = *(const short8*)&Bs[(wc * 32 + 16 + r) * LDST + q * 8];
        acc[0][0] = __builtin_amdgcn_mfma_f32_16x16x32_bf16(a0, b0, acc[0][0], 0, 0, 0);
        acc[0][1] = __builtin_amdgcn_mfma_f32_16x16x32_bf16(a0, b1, acc[0][1], 0, 0, 0);
        acc[1][0] = __builtin_amdgcn_mfma_f32_16x16x32_bf16(a1, b0, acc[1][0], 0, 0, 0);
        acc[1][1] = __builtin_amdgcn_mfma_f32_16x16x32_bf16(a1, b1, acc[1][1], 0, 0, 0);
        __syncthreads();
    }

#pragma unroll
    for (int c = 0; c < 2; c++) {
        int col = bn0 + wc * 32 + c * 16 + r;
        if (col >= Nn) continue;
#pragma unroll
        for (int i = 0; i < 2; i++) {
#pragma unroll
            for (int v = 0; v < 4; v++) {
                int row = bm0 + wr * 32 + i * 16 + q * 4 + v;
                if (row >= M) continue;
                if (OM == 1) C16[(size_t)row * ldc + col] = f2bf(acc[i][c][v]);
                else C16[(size_t)col * ldc + row * 20 + blockIdx.z] = f2bf(acc[i][c][v]);
            }
        }
    }
}

// fused reshape: W[32,750,8] -> Wr[750,256] for both conv weights
__global__ __launch_bounds__(256) void k_wcr_both(const float* __restrict__ Wc2, const float* __restrict__ Wc1,
                                                  float* __restrict__ Wc2r, float* __restrict__ Wc1r) {
    int cc = blockIdx.x, j = threadIdx.x;
    const float* W = (cc < 750) ? Wc2 : Wc1;
    float* Wr = (cc < 750) ? Wc2r : Wc1r;
    int c = (cc < 750) ? cc : cc - 750;
    Wr[(size_t)c * 256 + j] = W[(size_t)(j >> 3) * 6000 + c * 8 + (j & 7)];
}

// T[(v*256+o*8+k), j] = sum_l emb[v,l+k] * Wxt2[(o*121+l), j]
__global__ __launch_bounds__(128) void k_T_build(const float* __restrict__ emb, const float* __restrict__ Wxt2,
                                                 float* __restrict__ T) {
    __shared__ float el[128];
    int v = blockIdx.x >> 5, o = blockIdx.x & 31, j = threadIdx.x;
    el[j] = emb[(size_t)v * 128 + j];
    __syncthreads();
    float acc[8] = {};
    for (int l = 0; l < 121; l++) {
        float w = Wxt2[(size_t)(o * 121 + l) * 128 + j];
#pragma unroll
        for (int k = 0; k < 8; k++) acc[k] += el[l + k] * w;
    }
#pragma unroll
    for (int k = 0; k < 8; k++) T[(size_t)(v * 256 + o * 8 + k) * 128 + j] = acc[k];
}

// Bt[t*256 + o*8+k, j] = Wxt1[(o*13 + t-k)*128 + j] if 0<=t-k<13 else 0
__global__ __launch_bounds__(128) void k_bt_build(const float* __restrict__ Wxt1, float* __restrict__ Bt) {
    int ok = blockIdx.x, t = blockIdx.y, j = threadIdx.x;
    int o = ok >> 3, k = ok & 7, lpos = t - k;
    float v = (lpos >= 0 && lpos < 13) ? Wxt1[(size_t)(o * 13 + lpos) * 128 + j] : 0.f;
    Bt[(size_t)(t * 256 + ok) * 128 + j] = v;
}

// xt2[b,j] = b2v[j] + sum_c U16[c, t2[b,c], j]  -- bf16 U, short8 loads
__global__ __launch_bounds__(128) void k_u_gather16(const int* __restrict__ t2, const unsigned short* __restrict__ U,
                                                    const float* __restrict__ b2v, float* __restrict__ xc) {
    __shared__ int offs[752];
    __shared__ float red[8][128];
    int b = blockIdx.x, tid = threadIdx.x;
    int rg = tid >> 4, lane = tid & 15;
    const int* t2b = t2 + (size_t)b * 750;
    for (int i = tid; i < 750; i += 128) offs[i] = i * 3328 + t2b[i] * 128;
    __syncthreads();
    float a[8] = {};
#pragma unroll 4
    for (int i = rg; i < 750; i += 8) {
        short8 v = *(const short8*)&U[(size_t)offs[i] + lane * 8];
#pragma unroll
        for (int c = 0; c < 8; c++) a[c] += bf2f((unsigned short)v[c]);
    }
#pragma unroll
    for (int c = 0; c < 8; c++) red[rg][lane * 8 + c] = a[c];
    __syncthreads();
    float s = b2v[tid];
#pragma unroll
    for (int g = 0; g < 8; g++) s += red[g][tid];
    xc[(size_t)b * 384 + 256 + tid] = s;
}

// ---- conv-bias folds ----
__global__ void k_bias_init(const float* __restrict__ bxt1, const float* __restrict__ bxt2,
                            float* __restrict__ b1v, float* __restrict__ b2v) {
    int j = threadIdx.x;
    b1v[j] = bxt1[j];
    b2v[j] = bxt2[j];
}

// blocks 0-31: b1v += bc1[o]*colsum(Wxt1,o); blocks 32-63: b2v += bc2[o]*colsum(Wxt2,o)
__global__ __launch_bounds__(128) void k_bias_acc_both(const float* __restrict__ bc1, const float* __restrict__ Wxt1,
                                                       float* __restrict__ b1v,
                                                       const float* __restrict__ bc2, const float* __restrict__ Wxt2,
                                                       float* __restrict__ b2v) {
    int b = blockIdx.x, j = threadIdx.x;
    if (b < 32) {
        const float* p = Wxt1 + (size_t)b * 13 * 128 + j;
        float t = 0.f;
        for (int l = 0; l < 13; l++) t += p[(size_t)l * 128];
        atomicAdd(&b1v[j], bc1[b] * t);
    } else {
        int o = b - 32;
        const float* p = Wxt2 + (size_t)o * 121 * 128 + j;
        float t = 0.f;
        for (int l = 0; l < 121; l++) t += p[(size_t)l * 128];
        atomicAdd(&b2v[j], bc2[o] * t);
    }
}

// one-shot bias init: xc[:,0:128]=bg2, xc[:,128:256]=b1v, f2=bf2
__global__ __launch_bounds__(768) void k_initC(float* __restrict__ xc, float* __restrict__ f2,
                                               const float* __restrict__ bg2, const float* __restrict__ b1v,
                                               const float* __restrict__ bf2) {
    int b = blockIdx.x, t = threadIdx.x;
    if (t < 128) xc[(size_t)b * 384 + t] = bg2[t];
    else if (t < 256) xc[(size_t)b * 384 + t] = b1v[t - 128];
    else f2[(size_t)b * 512 + t - 256] = bf2[t - 256];
}

// out[b] = sum_j relu(f2[b,j]) * Wo[j] + bo
__global__ __launch_bounds__(64) void k_final(const float* __restrict__ f2, const float* __restrict__ Wo,
                                              const float* __restrict__ bo, float* __restrict__ out) {
    int b = blockIdx.x, lane = threadIdx.x;
    float s = 0.f;
    for (int j = lane; j < 512; j += 64) s += fmaxf(f2[(size_t)b * 512 + j], 0.f) * Wo[j];
    for (int off = 32; off; off >>= 1) s += __shfl_down(s, off);
    if (lane == 0) out[b] = s + bo[0];
}

extern "C" void kernel_launch(void* const* d_in, const int* in_sizes, int n_in,
                              void* d_out, int out_size, void* d_ws, size_t ws_size,
                              hipStream_t stream) {
    const float* x    = (const float*)d_in[0];
    const int*   ei   = (const int*)d_in[1];
    const float* t1   = (const float*)d_in[3];
    const int*   t2   = (const int*)d_in[4];
    const float* W1   = (const float*)d_in[5];
    const float* b1   = (const float*)d_in[6];
    const float* W2   = (const float*)d_in[7];
    const float* b2   = (const float*)d_in[8];
    const float* W3   = (const float*)d_in[9];
    const float* b3   = (const float*)d_in[10];
    const float* Wg1  = (const float*)d_in[11];
    const float* bg1  = (const float*)d_in[12];
    const float* Wg2  = (const float*)d_in[13];
    const float* bg2  = (const float*)d_in[14];
    const float* emb  = (const float*)d_in[15];
    const float* Wc2  = (const float*)d_in[16];
    const float* bc2  = (const float*)d_in[17];
    const float* Wxt2 = (const float*)d_in[18];
    const float* bxt2 = (const float*)d_in[19];
    const float* Wc1  = (const float*)d_in[20];
    const float* bc1  = (const float*)d_in[21];
    const float* Wxt1 = (const float*)d_in[22];
    const float* bxt1 = (const float*)d_in[23];
    const float* Wf1  = (const float*)d_in[24];
    const float* bf1  = (const float*)d_in[25];
    const float* Wf2  = (const float*)d_in[26];
    const float* bf2  = (const float*)d_in[27];
    const float* Wo   = (const float*)d_in[28];
    const float* bo   = (const float*)d_in[29];
    float* out = (float*)d_out;

    float* ws = (float*)d_ws;
    float* dinv  = ws + o_dinv;
    unsigned short* g312b = (unsigned short*)(ws + o_g312);   // 1024 x 320 bf16
    unsigned short* g1024b = (unsigned short*)(ws + o_g1024); // 1024 x 1024 bf16
    float* xc    = ws + o_xc;     // [1024 x 384] fp32
    unsigned short* f1b = (unsigned short*)(ws + o_f1);       // 1024 x 1024 bf16
    float* f2    = ws + o_f2;
    float* b1v   = ws + o_b1v;
    float* b2v   = ws + o_b2v;
    int* csrOff  = (int*)(ws + o_iws);
    int* csrCur  = csrOff + (NN + 1);
    int* csrSrc  = csrCur + NN;
    int* blockSum = (int*)(ws + o_f1 + 600000);  // scratch, dead before f1b written
    int* blockOff = blockSum + 40;
    float* bufA  = ws + o_bufA;
    float* bufB  = ws + o_bufB;
    float* T    = bufA;
    unsigned short* U16  = (unsigned short*)(bufA + 851968);
    unsigned short* Vt16 = (unsigned short*)(bufA + 2200000);  // 128 x 15360 bf16
    unsigned short* Wt   = (unsigned short*)(bufA + 3200000);  // transposed weights
    float* Wc2r = bufA + 4000000;
    float* Wc1r = bufA + 4200000;
    float* Btb  = bufA + 4400000;
    // bf16 node pipeline (inside bufB)
    unsigned* aggb = (unsigned*)bufB;                          // NN*80 uints max
    unsigned short* h16 = (unsigned short*)(bufB + 5500000);   // up to NN*312
    float* Pt1 = bufB;   // t1 split-K partials (48*1024*128 fp32) -- aggb/h16 dead by then

    unsigned short* W1t  = Wt + 0;
    unsigned short* W2t  = Wt + 12288;
    unsigned short* W3t  = Wt + 30720;
    unsigned short* Wg1t = Wt + 81920;
    unsigned short* Wg2t = Wt + 409600;
    unsigned short* Wf1t = Wt + 540672;
    unsigned short* Wf2t = Wt + 933888;

    // ---- CSR build + degree + weight converts ----
    hipMemsetAsync(csrCur, 0, NN * sizeof(int), stream);
    k_hist<<<NE / 256, 256, 0, stream>>>(ei + NE, csrCur);
    k_scan1<<<40, 1024, 0, stream>>>(csrCur, csrOff, blockSum, dinv);
    k_scan2<<<1, 64, 0, stream>>>(blockSum, blockOff);
    k_scan3<<<40, 1024, 0, stream>>>(csrOff, csrCur, blockOff);
    k_fill<<<NE / 256, 256, 0, stream>>>(ei, csrCur, csrSrc);
    k_cvt_wt<<<3328, 256, 0, stream>>>(W1, W2, W3, Wg1, Wg2, Wf1, Wf2, Wt);

    // ---- GCN layers: bf16 pipeline, aggregate input (2-wide), GEMM(bias+relu) ----
    k_agg_x<<<NN, 64, 0, stream>>>(x, dinv, csrOff, csrSrc, aggb);
    gemm_bt<true, true, false, true><<<dim3(2, 640, 1), 256, 0, stream>>>(
        aggb, W1t, b1, h16, 78, 96, 96, 96, 96, 96, 96, 96);
    k_agg16<<<NN, 64, 0, stream>>>((unsigned*)h16, dinv, csrOff, csrSrc, aggb, 48);
    gemm_bt<true, true, false, true><<<dim3(3, 640, 1), 256, 0, stream>>>(
        aggb, W2t, b2, h16, 156, 160, 96, 96, 96, 96, 160, 96);
    k_agg16<<<NN, 128, 0, stream>>>((unsigned*)h16, dinv, csrOff, csrSrc, aggb, 80);
    gemm_bt<true, true, false, true><<<dim3(5, 640, 1), 256, 0, stream>>>(
        aggb, W3t, b3, h16, 312, 312, 160, 160, 160, 160, 312, 160);
    k_segmax16<<<NB, 320, 0, stream>>>(h16, g312b);
    gemm_bt<true, true, false, true><<<dim3(16, 16, 1), 256, 0, stream>>>(
        g312b, Wg1t, bg1, g1024b, 1024, 1024, 320, 320, 320, 320, 1024, 320);

    // fused conv biases, then one-shot C-inits
    k_bias_init<<<1, 128, 0, stream>>>(bxt1, bxt2, b1v, b2v);
    k_bias_acc_both<<<64, 128, 0, stream>>>(bc1, Wxt1, b1v, bc2, Wxt2, b2v);
    k_initC<<<NB, 768, 0, stream>>>(xc, f2, bg2, b1v, bf2);

    // xc[:,0:128] = g1024 @ Wg2 + bg2   (split-K atomic)
    gemm_bt<true, false, true, false><<<dim3(2, 16, 8), 256, 0, stream>>>(
        g1024b, Wg2t, nullptr, xc + 0, 128, 128, 1024, 1024, 1024, 1024, 384, 128);

    // ---- protein branch 2: U16 = Wc2r @ T (26-batch, bf16 out), then vector gather-sum ----
    k_wcr_both<<<1500, 256, 0, stream>>>(Wc2, Wc1, Wc2r, Wc1r);
    k_T_build<<<26 * 32, 128, 0, stream>>>(emb, Wxt2, T);
    gemm_mfma_batch<1><<<dim3(2, 12, 26), 256, 0, stream>>>(Wc2r, T, U16, 750, 128, 256, 3328, 32768, 128);
    k_u_gather16<<<NB, 128, 0, stream>>>(t2, U16, b2v, xc);

    // ---- protein branch 1: Vt16 = (Wc1r @ Bt)^T packed (20-batch, K-stride 15360), then
    //      P = t1 @ Vt^T split-K partials, then reduce into xc[:,128:256] ----
    k_bt_build<<<dim3(256, 20), 128, 0, stream>>>(Wxt1, Btb);
    hipMemsetAsync(Vt16, 0, (size_t)128 * 15360 * 2, stream);
    gemm_mfma_batch<2><<<dim3(2, 12, 20), 256, 0, stream>>>(Wc1r, Btb, Vt16, 750, 128, 256, 15360, 32768, 0);
    gemm_t1<<<dim3(T1S, 16, 1), 256, 0, stream>>>(t1, Vt16, Pt1);
    k_red_t1<<<NB, 128, 0, stream>>>(Pt1, xc);

    // ---- head ----
    gemm_bt<false, true, false, true><<<dim3(16, 16, 1), 256, 0, stream>>>(
        xc, Wf1t, bf1, f1b, 1024, 1024, 384, 384, 384, 384, 1024, 384);
    gemm_bt<true, false, true, false><<<dim3(8, 16, 4), 256, 0, stream>>>(
        f1b, Wf2t, nullptr, f2, 512, 512, 1024, 1024, 1024, 1024, 512, 256);
    k_final<<<NB, 64, 0, stream>>>(f2, Wo, bo, out);
}